// Round 15
// baseline (258.043 us; speedup 1.0000x reference)
//
#include <hip/hip_runtime.h>
#include <hip/hip_fp16.h>
#include <cfloat>

// NearestNeighborGraph: S=16, N=2048, D=64, K=16.
// Round-23: 16 waves/CU at constant traffic (the lever r21/r22 both missed).
//  Invariant: scan traffic = const/RB (256MB at RB=64); waves/CU = 128*NWV/RB.
//  r22 (NWV=4): grid-limited to 8 waves/CU -> null. r21 (RB=128): 256 blocks
//  = 1/CU, LOWER occupancy, plus RSTR=128 power-of-2 ring stride -> 64-way
//  LDS conflicts in rescue (1.4M counted) -> 5x regression despite passing.
//  This round: RB=64, NWV=8 (512 threads), JW=256, grid=512 = 2 blocks/CU
//  = 16 waves/CU at r20's exact 256MB traffic. RSTR=137 (odd). k=2 fold:
//  8 substreams x top-2 = 16 elements -> tau = max_w(2nd-of-256) + MARGIN
//  bounds the row's approx 16th (same margin algebra as r16/r20). RCAP=136
//  + full-row exact brute-force fallback on overflow -> correctness
//  unconditional on tau quality. Rescue: 8 workers/row, 3-level merge;
//  md/mi alias the dead ring. LDS 45.8KB. Exact fp32 rescue chains
//  bit-identical to all passing rounds.

typedef _Float16 half8 __attribute__((ext_vector_type(8)));
typedef _Float16 half4 __attribute__((ext_vector_type(4)));
typedef float    f32x4 __attribute__((ext_vector_type(4)));

constexpr int NS = 16, NP = 2048, ND = 64, KK = 16;
constexpr int NWV = 8;              // waves per block
constexpr int NT  = NWV * 64;       // 512 threads
constexpr int RB  = 64;             // rows (i) per block
constexpr int ITN = RB / 16;        // 4 i-tiles
constexpr int JW  = NP / NWV;       // 256 j per wave
constexpr int NJT = JW / 16;        // 16 j-tiles per wave
constexpr int MS  = 17;             // merge-tree stride
constexpr int RCAP = 136;           // candidate ring slots per row
constexpr int RSTR = 137;           // ring stride (odd -> bank-spread)
constexpr float MARGIN = 1.0f;

// ---- prep: 16 rows/block; coalesced f16 copy + rotated-chain x2 ----
__global__ __launch_bounds__(256)
void prep_kernel(const float* __restrict__ h, float* __restrict__ x2,
                 _Float16* __restrict__ hh)
{
    const int b = blockIdx.x;                 // 0..2047, 16 rows each
    const int t = threadIdx.x;
    const size_t base = (size_t)b * 16 * ND;  // flat float offset

    float4 v = *(const float4*)(h + base + (size_t)t * 4);
    half4 p;
    p[0] = (_Float16)v.x; p[1] = (_Float16)v.y;
    p[2] = (_Float16)v.z; p[3] = (_Float16)v.w;
    *(half4*)(hh + base + (size_t)t * 4) = p;

    // x2: rotated chain, bit-identical to rounds 1-22 (1 thread per row)
    if (t < 16) {
        const int g = b * 16 + t;             // flat row
        const float4* row = (const float4*)(h + (size_t)g * ND);
        const int ph = g & 15;
        float a0 = 0.f, a1 = 0.f, a2 = 0.f, a3 = 0.f;
        #pragma unroll
        for (int k = 0; k < 16; ++k) {
            float4 u = row[(k + ph) & 15];
            a0 = fmaf(u.x, u.x, a0); a1 = fmaf(u.y, u.y, a1);
            a2 = fmaf(u.z, u.z, a2); a3 = fmaf(u.w, u.w, a3);
        }
        x2[g] = (a0 + a1) + (a2 + a3);
    }
}

// lexicographic (d2, j) insert == top_k tie-break (lowest index on equal d2)
__device__ __forceinline__ bool lexlt(float a, int ja, float b, int jb)
{
    return (a < b) || (a == b && ja < jb);
}
__device__ __forceinline__ void insert16x(float (&d)[KK], int (&ix)[KK],
                                          float v, int j)
{
    #pragma unroll
    for (int p = KK - 1; p > 0; --p) {
        bool sh = lexlt(v, j, d[p - 1], ix[p - 1]);
        bool he = lexlt(v, j, d[p], ix[p]);
        float nd = sh ? d[p - 1] : (he ? v : d[p]);
        int   ni = sh ? ix[p - 1] : (he ? j : ix[p]);
        d[p] = nd; ix[p] = ni;
    }
    if (lexlt(v, j, d[0], ix[0])) { d[0] = v; ix[0] = j; }
}

__global__ __launch_bounds__(NT, 2)
void knn_mfma(const float* __restrict__ h, const _Float16* __restrict__ hh,
              const float* __restrict__ x2g, float* __restrict__ out)
{
    // 11456 floats = 45824 B -> 2 blocks/CU (grid 512 = exactly 2/CU)
    __shared__ __align__(16) float smem[11456];
    float* ldsx2  = smem;                    // [0,2048)
    float* mw     = smem + 2048;             // [2048,2560)  8 waves x 64 rows
    float* ldsthr = smem + 2560;             // [2560,2624)
    int*   rcnt   = (int*)(smem + 2624);     // [2624,2688)
    int*   ring   = (int*)(smem + 2688);     // [2688,11456) 64 x 137
    // aliases (ring dead after rescue reads, which finish pre-barrier):
    float* md     = (float*)ring;            // 4 x 64 x 17 = 4352 floats
    int*   mi     = ring + 4352;             // 4352 ints (8704 <= 8768)

    const int t   = threadIdx.x;
    const int ln  = t & 63;
    const int qd  = ln >> 4;                 // j-subslice within wave
    const int cl  = ln & 15;                 // i within 16-tile (swapped D col)
    const int q   = t >> 6;                  // wave id (j-eighth), 0..7
    // XCD sample-affinity swizzle (bijective): sample s -> XCD (s&7).
    const int bid = blockIdx.x;              // 0..511
    const int xcd = bid & 7;
    const int kb  = bid >> 3;                // 0..63
    const int s   = xcd + ((kb & 1) << 3);   // 0..15
    const int rb  = kb >> 1;                 // 0..31
    const int rowbase = rb * RB;             // block's 64 i-rows (sample-local)
    const float*    __restrict__ hs  = h  + (size_t)s * NP * ND;
    const _Float16* __restrict__ hhs = hh + (size_t)s * NP * ND;

    // stage sample x2 (512 threads x float4 = 2048); init ring counts
    ((float4*)ldsx2)[t] = ((const float4*)(x2g + s * NP))[t];
    if (t < RB) rcnt[t] = 0;

    // i-fragments (the MFMA *B* operand): lane holds I[n=cl][k=qd*8..+7]
    half8 ifr[ITN][2];
    #pragma unroll
    for (int it = 0; it < ITN; ++it) {
        const _Float16* ap = hhs + (size_t)(rowbase + it * 16 + cl) * ND + qd * 8;
        ifr[it][0] = *(const half8*)(ap);
        ifr[it][1] = *(const half8*)(ap + 32);
    }
    __syncthreads();

    const int jbase = q * JW;
    const _Float16* __restrict__ jrow0 = hhs + (size_t)(jbase + cl) * ND + qd * 8;

    // fold state: per-lane sorted top-2 of d2' = x2j - 2*dot, per i-tile
    float t1[ITN], t2[ITN];
    #pragma unroll
    for (int it = 0; it < ITN; ++it) { t1[it] = FLT_MAX; t2[it] = FLT_MAX; }

    // ===== stage A: fold-only scan (16 tiles, 4 i-tiles per j-load) =========
    #pragma unroll 2
    for (int jt = 0; jt < NJT; ++jt) {
        const _Float16* bp = jrow0 + (size_t)jt * (16 * ND);
        half8 jlo = *(const half8*)(bp);
        half8 jhi = *(const half8*)(bp + 32);
        f32x4 xq = *(const f32x4*)(ldsx2 + jbase + jt * 16 + qd * 4);

        #pragma unroll
        for (int it = 0; it < ITN; ++it) {
            f32x4 acc;
            acc = __builtin_amdgcn_mfma_f32_16x16x32_f16(
                      jlo, ifr[it][0], (f32x4){0.f, 0.f, 0.f, 0.f}, 0, 0, 0);
            acc = __builtin_amdgcn_mfma_f32_16x16x32_f16(
                      jhi, ifr[it][1], acc, 0, 0, 0);
            #pragma unroll
            for (int r = 0; r < 4; ++r) {
                float v  = fmaf(-2.f, acc[r], xq[r]);
                float n1 = fminf(t1[it], v);
                float n2 = __builtin_amdgcn_fmed3f(t1[it], t2[it], v);
                t1[it] = n1; t2[it] = n2;
            }
        }
    }

    // merge the 4 qd sub-lists (sorted 2s) -> wave's exact top-2 of 256
    #pragma unroll
    for (int it = 0; it < ITN; ++it) {
        #pragma unroll
        for (int lvl = 0; lvl < 2; ++lvl) {
            const int mask = 16 << lvl;
            float b1 = __shfl_xor(t1[it], mask), b2 = __shfl_xor(t2[it], mask);
            float m1 = fminf(t1[it], b2), m2 = fminf(t2[it], b1);
            t1[it] = fminf(m1, m2);
            t2[it] = fmaxf(m1, m2);
        }
    }
    if (qd == 0) {
        #pragma unroll
        for (int it = 0; it < ITN; ++it)
            mw[q * RB + it * 16 + cl] = t2[it];   // 2nd of wave's 256, row
    }
    __syncthreads();
    // tau = max over 8 waves of (exact 2nd of 256-substream) + margin
    // (union of 8 top-2s = 16 in-row elements <= M -> row approx-16th <= M)
    if (q == 0) {
        float m = mw[ln];
        #pragma unroll
        for (int w = 1; w < NWV; ++w) m = fmaxf(m, mw[w * RB + ln]);
        ldsthr[ln] = m + MARGIN;
    }
    __syncthreads();

    // tau for lane's 4 i-rows
    float thrv[ITN];
    #pragma unroll
    for (int it = 0; it < ITN; ++it) thrv[it] = ldsthr[it * 16 + cl];

    // ===== stage B: re-scan, filter d2' < tau into candidate rings ==========
    #pragma unroll 2
    for (int jt = 0; jt < NJT; ++jt) {
        const _Float16* bp = jrow0 + (size_t)jt * (16 * ND);
        half8 jlo = *(const half8*)(bp);
        half8 jhi = *(const half8*)(bp + 32);
        f32x4 xq = *(const f32x4*)(ldsx2 + jbase + jt * 16 + qd * 4);
        const int j0 = jbase + jt * 16;

        #pragma unroll
        for (int it = 0; it < ITN; ++it) {
            f32x4 acc;
            acc = __builtin_amdgcn_mfma_f32_16x16x32_f16(
                      jlo, ifr[it][0], (f32x4){0.f, 0.f, 0.f, 0.f}, 0, 0, 0);
            acc = __builtin_amdgcn_mfma_f32_16x16x32_f16(
                      jhi, ifr[it][1], acc, 0, 0, 0);
            #pragma unroll
            for (int r = 0; r < 4; ++r) {
                float d2 = fmaf(-2.f, acc[r], xq[r]);
                if (d2 < thrv[it]) {
                    int rw = it * 16 + cl;
                    int slot = atomicAdd(&rcnt[rw], 1);
                    if (slot < RCAP) ring[rw * RSTR + slot] = j0 + qd * 4 + r;
                }
            }
        }
    }
    __syncthreads();

    // ========== rescue: exact fp32 recompute of candidates ===============
    // row = ln (0..63); 8 workers per row: wave q takes slots q, q+8, ...
    const int row   = ln;
    const int myrow = rowbase + row;
    float4 A[16];
    {
        const float4* ra = (const float4*)(hs + (size_t)myrow * ND);
        #pragma unroll
        for (int k = 0; k < 16; ++k) A[k] = ra[k];
    }
    float x2i;   // ascending chain (exact round-1 i-side value)
    {
        float a0 = 0.f, a1 = 0.f, a2 = 0.f, a3 = 0.f;
        #pragma unroll
        for (int k = 0; k < 16; ++k) {
            a0 = fmaf(A[k].x, A[k].x, a0); a1 = fmaf(A[k].y, A[k].y, a1);
            a2 = fmaf(A[k].z, A[k].z, a2); a3 = fmaf(A[k].w, A[k].w, a3);
        }
        x2i = (a0 + a1) + (a2 + a3);
    }
    float dist[KK]; int idx[KK];
    #pragma unroll
    for (int k = 0; k < KK; ++k) { dist[k] = FLT_MAX; idx[k] = 0; }

    const int rawc = rcnt[row];
    if (rawc <= RCAP) {
        // normal path: exact recompute of ring candidates
        #pragma unroll 1
        for (int k = q; k < rawc; k += NWV) {
            int j = ring[row * RSTR + k];
            const float4* cv = (const float4*)(hs + (size_t)j * ND);
            float a0 = 0.f, a1 = 0.f, a2 = 0.f, a3 = 0.f;
            #pragma unroll
            for (int kk = 0; kk < 16; ++kk) {
                float4 c = cv[kk];
                a0 = fmaf(A[kk].x, c.x, a0); a1 = fmaf(A[kk].y, c.y, a1);
                a2 = fmaf(A[kk].z, c.z, a2); a3 = fmaf(A[kk].w, c.w, a3);
            }
            float dotv = (a0 + a1) + (a2 + a3);
            float d2 = fmaf(-2.0f, dotv, x2i + ldsx2[j]);
            if (lexlt(d2, j, dist[KK - 1], idx[KK - 1]))
                insert16x(dist, idx, d2, j);
        }
    } else {
        // overflow fallback (rare): ring incomplete -> exact brute force of
        // the full row (reference by construction). Ring entries skipped.
        #pragma unroll 1
        for (int j = q; j < NP; j += NWV) {
            const float4* cv = (const float4*)(hs + (size_t)j * ND);
            float a0 = 0.f, a1 = 0.f, a2 = 0.f, a3 = 0.f;
            #pragma unroll
            for (int kk = 0; kk < 16; ++kk) {
                float4 c = cv[kk];
                a0 = fmaf(A[kk].x, c.x, a0); a1 = fmaf(A[kk].y, c.y, a1);
                a2 = fmaf(A[kk].z, c.z, a2); a3 = fmaf(A[kk].w, c.w, a3);
            }
            float dotv = (a0 + a1) + (a2 + a3);
            float d2 = fmaf(-2.0f, dotv, x2i + ldsx2[j]);
            if (lexlt(d2, j, dist[KK - 1], idx[KK - 1]))
                insert16x(dist, idx, d2, j);
        }
    }

    // ---- final exact merge (lex): 3 LDS levels over 8 waves (gated) ----
    // md/mi alias the ring: all ring reads completed before this barrier.
    __syncthreads();
    #pragma unroll 1
    for (int lvl = 0; lvl < 3; ++lvl) {
        const int step = 1 << lvl;
        const int m    = (step << 1) - 1;
        const bool pub = ((q & m) == step);
        const int reg  = q >> (lvl + 1);
        if (pub) {
            #pragma unroll
            for (int k = 0; k < KK; ++k) {
                md[(reg * RB + row) * MS + k] = dist[k];
                mi[(reg * RB + row) * MS + k] = idx[k];
            }
        }
        __syncthreads();
        if ((q & m) == 0) {
            #pragma unroll 1
            for (int k = 0; k < KK; ++k) {
                float v  = md[(reg * RB + row) * MS + k];
                int   jv = mi[(reg * RB + row) * MS + k];
                bool need = lexlt(v, jv, dist[KK - 1], idx[KK - 1]);
                if (!__any(need)) break;
                if (need) insert16x(dist, idx, v, jv);
            }
        }
        __syncthreads();
    }

    // ---- output (wave 0) ----
    if (q == 0) {
        const int off = s * NP;
        const size_t rg = (size_t)off + myrow;
        float* o0 = out + rg * KK;
        float* o1 = out + (size_t)NS * NP * KK + rg * KK;
        float* o2 = out + (size_t)2 * NS * NP * KK + rg * KK;
        #pragma unroll
        for (int k = 0; k < KK; ++k) o0[k] = dist[k];
        #pragma unroll
        for (int k = 0; k < KK; ++k) o1[k] = (float)(idx[k] + off);
        #pragma unroll
        for (int k = 0; k < KK; ++k) o2[k] = (float)(off + myrow);
    }
}

extern "C" void kernel_launch(void* const* d_in, const int* in_sizes, int n_in,
                              void* d_out, int out_size, void* d_ws, size_t ws_size,
                              hipStream_t stream)
{
    const float* h = (const float*)d_in[0];
    float* out = (float*)d_out;
    float*    x2 = (float*)d_ws;                     // 32768 floats (128 KB)
    _Float16* hh = (_Float16*)(x2 + NS * NP);        // 16*2048*64 halves (4 MB)

    hipLaunchKernelGGL(prep_kernel, dim3(NS * NP / 16), dim3(256), 0, stream,
                       h, x2, hh);
    hipLaunchKernelGGL(knn_mfma, dim3(NS * (NP / RB)), dim3(NT), 0, stream,
                       h, hh, x2, out);
}

// Round 17
// 177.950 us; speedup vs baseline: 1.4501x; 1.4501x over previous
//
#include <hip/hip_runtime.h>
#include <hip/hip_fp16.h>
#include <cfloat>

// NearestNeighborGraph: S=16, N=2048, D=64, K=16.
// Round-25 (resubmit of r24/r20; r16-round bench died to container-acquisition
// infra failure, same mode as round 1 — kernel is byte-identical to the
// r20 run that PASSED at 123us knn / 178.2us total).
//  r20 = confirmed local optimum:
//   - 2-pass scan, RB=64 (4 i-tiles amortize each j-fragment load),
//   - swapped-operand MFMA (reduction axis lane-local, top-4 via fmed3),
//   - tau = max_w(exact 4th of wave's 512-substream) + MARGIN,
//   - ring filter + exact fp32 rescue (bit-identical round-1 chains, lex
//     tie-break == jax top_k) + full-row brute-force on ring overflow.
//  Ledger of refuted neighbors: +occupancy 3blk/CU (r22 null), 8-wave
//  blocks (r23 -65%), RB=128 (r21 -5x), 1.5-pass (r19 -8%), fusion
//  (r14 -85%, r15 broken under graph capture).

typedef _Float16 half8 __attribute__((ext_vector_type(8)));
typedef _Float16 half4 __attribute__((ext_vector_type(4)));
typedef float    f32x4 __attribute__((ext_vector_type(4)));

constexpr int NS = 16, NP = 2048, ND = 64, KK = 16;
constexpr int NWV = 4;              // waves per block
constexpr int NT  = NWV * 64;       // 256 threads
constexpr int RB  = 64;             // rows (i) per block
constexpr int ITN = RB / 16;        // 4 i-tiles
constexpr int JW  = NP / NWV;       // 512 j per wave
constexpr int NJT = JW / 16;        // 32 j-tiles per wave
constexpr int MS  = 17;             // merge-tree stride
constexpr int RCAP = 176;           // candidate ring slots per row
constexpr int RSTR = RCAP + 1;      // ring stride (177, odd -> bank-spread)
constexpr float MARGIN = 1.0f;

// ---- prep: 16 rows/block; coalesced f16 copy + rotated-chain x2 ----
__global__ __launch_bounds__(256)
void prep_kernel(const float* __restrict__ h, float* __restrict__ x2,
                 _Float16* __restrict__ hh)
{
    const int b = blockIdx.x;                 // 0..2047, 16 rows each
    const int t = threadIdx.x;
    const size_t base = (size_t)b * 16 * ND;  // flat float offset

    float4 v = *(const float4*)(h + base + (size_t)t * 4);
    half4 p;
    p[0] = (_Float16)v.x; p[1] = (_Float16)v.y;
    p[2] = (_Float16)v.z; p[3] = (_Float16)v.w;
    *(half4*)(hh + base + (size_t)t * 4) = p;

    // x2: rotated chain, bit-identical to all passing rounds (1 thr/row)
    if (t < 16) {
        const int g = b * 16 + t;             // flat row
        const float4* row = (const float4*)(h + (size_t)g * ND);
        const int ph = g & 15;
        float a0 = 0.f, a1 = 0.f, a2 = 0.f, a3 = 0.f;
        #pragma unroll
        for (int k = 0; k < 16; ++k) {
            float4 u = row[(k + ph) & 15];
            a0 = fmaf(u.x, u.x, a0); a1 = fmaf(u.y, u.y, a1);
            a2 = fmaf(u.z, u.z, a2); a3 = fmaf(u.w, u.w, a3);
        }
        x2[g] = (a0 + a1) + (a2 + a3);
    }
}

// lexicographic (d2, j) insert == top_k tie-break (lowest index on equal d2)
__device__ __forceinline__ bool lexlt(float a, int ja, float b, int jb)
{
    return (a < b) || (a == b && ja < jb);
}
__device__ __forceinline__ void insert16x(float (&d)[KK], int (&ix)[KK],
                                          float v, int j)
{
    #pragma unroll
    for (int p = KK - 1; p > 0; --p) {
        bool sh = lexlt(v, j, d[p - 1], ix[p - 1]);
        bool he = lexlt(v, j, d[p], ix[p]);
        float nd = sh ? d[p - 1] : (he ? v : d[p]);
        int   ni = sh ? ix[p - 1] : (he ? j : ix[p]);
        d[p] = nd; ix[p] = ni;
    }
    if (lexlt(v, j, d[0], ix[0])) { d[0] = v; ix[0] = j; }
}

// in-place bitonic merge of two sorted-4 lists across lane-xor 'mask'
__device__ __forceinline__ void bitonic4(float &a1, float &a2, float &a3,
                                         float &a4, int mask)
{
    float b1 = __shfl_xor(a1, mask), b2 = __shfl_xor(a2, mask);
    float b3 = __shfl_xor(a3, mask), b4 = __shfl_xor(a4, mask);
    float m1 = fminf(a1, b4), m2 = fminf(a2, b3);
    float m3 = fminf(a3, b2), m4 = fminf(a4, b1);
    float u1 = fminf(m1, m3), u3 = fmaxf(m1, m3);
    float u2 = fminf(m2, m4), u4 = fmaxf(m2, m4);
    a1 = fminf(u1, u2); a2 = fmaxf(u1, u2);
    a3 = fminf(u3, u4); a4 = fmaxf(u3, u4);
}

__global__ __launch_bounds__(NT, 2)
void knn_mfma(const float* __restrict__ h, const _Float16* __restrict__ hh,
              const float* __restrict__ x2g, float* __restrict__ out)
{
    // 18112 floats = 72448 B -> 2 blocks/CU
    __shared__ __align__(16) float smem[18112];
    float* ldsx2  = smem;                    // [0,2048)
    float* mw     = smem + 2048;             // [2048,2304)   4 waves x 64 rows
    float* ldsthr = smem + 2304;             // [2304,2368)
    int*   rcnt   = (int*)(smem + 2368);     // [2368,2432)
    int*   ring   = (int*)(smem + 2432);     // [2432,13760)  64 x 177
    float* md     = smem + 13760;            // [13760,15936) 2 x 64 x 17
    int*   mi     = (int*)(smem + 15936);    // [15936,18112)

    const int t   = threadIdx.x;
    const int ln  = t & 63;
    const int qd  = ln >> 4;                 // j-subslice within wave
    const int cl  = ln & 15;                 // i within 16-tile (swapped D col)
    const int q   = t >> 6;                  // wave id (j-quarter)
    // XCD sample-affinity swizzle (bijective): sample s -> XCD (s&7).
    const int bid = blockIdx.x;              // 0..511
    const int xcd = bid & 7;
    const int kb  = bid >> 3;                // 0..63
    const int s   = xcd + ((kb & 1) << 3);   // 0..15
    const int rb  = kb >> 1;                 // 0..31
    const int rowbase = rb * RB;             // block's 64 i-rows (sample-local)
    const float*    __restrict__ hs  = h  + (size_t)s * NP * ND;
    const _Float16* __restrict__ hhs = hh + (size_t)s * NP * ND;

    // stage sample x2; init ring counts
    ((float4*)ldsx2)[t]       = ((const float4*)(x2g + s * NP))[t];
    ((float4*)ldsx2)[t + 256] = ((const float4*)(x2g + s * NP))[t + 256];
    if (t < RB) rcnt[t] = 0;

    // i-fragments (the MFMA *B* operand): lane holds I[n=cl][k=qd*8..+7]
    half8 ifr[ITN][2];
    #pragma unroll
    for (int it = 0; it < ITN; ++it) {
        const _Float16* ap = hhs + (size_t)(rowbase + it * 16 + cl) * ND + qd * 8;
        ifr[it][0] = *(const half8*)(ap);
        ifr[it][1] = *(const half8*)(ap + 32);
    }
    __syncthreads();

    const int jbase = q * JW;
    const _Float16* __restrict__ jrow0 = hhs + (size_t)(jbase + cl) * ND + qd * 8;

    // fold state: per-lane sorted top-4 of d2' = x2j - 2*dot, per i-tile
    float t1[ITN], t2[ITN], t3[ITN], t4[ITN];
    #pragma unroll
    for (int it = 0; it < ITN; ++it)
        { t1[it] = FLT_MAX; t2[it] = FLT_MAX; t3[it] = FLT_MAX; t4[it] = FLT_MAX; }

    // ===== stage A: fold-only scan (32 tiles, 4 i-tiles per j-load) =========
    #pragma unroll 2
    for (int jt = 0; jt < NJT; ++jt) {
        const _Float16* bp = jrow0 + (size_t)jt * (16 * ND);
        half8 jlo = *(const half8*)(bp);
        half8 jhi = *(const half8*)(bp + 32);
        f32x4 xq = *(const f32x4*)(ldsx2 + jbase + jt * 16 + qd * 4);

        #pragma unroll
        for (int it = 0; it < ITN; ++it) {
            f32x4 acc;
            acc = __builtin_amdgcn_mfma_f32_16x16x32_f16(
                      jlo, ifr[it][0], (f32x4){0.f, 0.f, 0.f, 0.f}, 0, 0, 0);
            acc = __builtin_amdgcn_mfma_f32_16x16x32_f16(
                      jhi, ifr[it][1], acc, 0, 0, 0);
            #pragma unroll
            for (int r = 0; r < 4; ++r) {
                float v  = fmaf(-2.f, acc[r], xq[r]);
                float n1 = fminf(t1[it], v);
                float n2 = __builtin_amdgcn_fmed3f(t1[it], t2[it], v);
                float n3 = __builtin_amdgcn_fmed3f(t2[it], t3[it], v);
                float n4 = __builtin_amdgcn_fmed3f(t3[it], t4[it], v);
                t1[it] = n1; t2[it] = n2; t3[it] = n3; t4[it] = n4;
            }
        }
    }

    // merge the 4 qd sub-lists (sorted 4s) -> wave's exact top-4 of 512
    #pragma unroll
    for (int it = 0; it < ITN; ++it) {
        bitonic4(t1[it], t2[it], t3[it], t4[it], 16);
        bitonic4(t1[it], t2[it], t3[it], t4[it], 32);
    }
    if (qd == 0) {
        #pragma unroll
        for (int it = 0; it < ITN; ++it)
            mw[q * RB + it * 16 + cl] = t4[it];   // 4th of wave's 512, row
    }
    __syncthreads();
    // tau = max over 4 waves of (exact 4th of 512-substream) + margin
    if (q == 0) {
        float m0 = mw[ln],            m1 = mw[RB + ln];
        float m2 = mw[2 * RB + ln],   m3 = mw[3 * RB + ln];
        ldsthr[ln] = fmaxf(fmaxf(m0, m1), fmaxf(m2, m3)) + MARGIN;
    }
    __syncthreads();

    // tau for lane's 4 i-rows
    float thrv[ITN];
    #pragma unroll
    for (int it = 0; it < ITN; ++it) thrv[it] = ldsthr[it * 16 + cl];

    // ===== stage B: re-scan, filter d2' < tau into candidate rings ==========
    #pragma unroll 2
    for (int jt = 0; jt < NJT; ++jt) {
        const _Float16* bp = jrow0 + (size_t)jt * (16 * ND);
        half8 jlo = *(const half8*)(bp);
        half8 jhi = *(const half8*)(bp + 32);
        f32x4 xq = *(const f32x4*)(ldsx2 + jbase + jt * 16 + qd * 4);
        const int j0 = jbase + jt * 16;

        #pragma unroll
        for (int it = 0; it < ITN; ++it) {
            f32x4 acc;
            acc = __builtin_amdgcn_mfma_f32_16x16x32_f16(
                      jlo, ifr[it][0], (f32x4){0.f, 0.f, 0.f, 0.f}, 0, 0, 0);
            acc = __builtin_amdgcn_mfma_f32_16x16x32_f16(
                      jhi, ifr[it][1], acc, 0, 0, 0);
            #pragma unroll
            for (int r = 0; r < 4; ++r) {
                float d2 = fmaf(-2.f, acc[r], xq[r]);
                if (d2 < thrv[it]) {
                    int rw = it * 16 + cl;
                    int slot = atomicAdd(&rcnt[rw], 1);
                    if (slot < RCAP) ring[rw * RSTR + slot] = j0 + qd * 4 + r;
                }
            }
        }
    }
    __syncthreads();

    // ========== rescue: exact fp32 recompute of candidates ===============
    // row = ln (0..63); 4 workers per row: wave q takes slots q, q+4, ...
    const int row   = ln;
    const int myrow = rowbase + row;
    float4 A[16];
    {
        const float4* ra = (const float4*)(hs + (size_t)myrow * ND);
        #pragma unroll
        for (int k = 0; k < 16; ++k) A[k] = ra[k];
    }
    float x2i;   // ascending chain (exact round-1 i-side value)
    {
        float a0 = 0.f, a1 = 0.f, a2 = 0.f, a3 = 0.f;
        #pragma unroll
        for (int k = 0; k < 16; ++k) {
            a0 = fmaf(A[k].x, A[k].x, a0); a1 = fmaf(A[k].y, A[k].y, a1);
            a2 = fmaf(A[k].z, A[k].z, a2); a3 = fmaf(A[k].w, A[k].w, a3);
        }
        x2i = (a0 + a1) + (a2 + a3);
    }
    float dist[KK]; int idx[KK];
    #pragma unroll
    for (int k = 0; k < KK; ++k) { dist[k] = FLT_MAX; idx[k] = 0; }

    const int rawc = rcnt[row];
    if (rawc <= RCAP) {
        // normal path: exact recompute of ring candidates
        #pragma unroll 1
        for (int k = q; k < rawc; k += NWV) {
            int j = ring[row * RSTR + k];
            const float4* cv = (const float4*)(hs + (size_t)j * ND);
            float a0 = 0.f, a1 = 0.f, a2 = 0.f, a3 = 0.f;
            #pragma unroll
            for (int kk = 0; kk < 16; ++kk) {
                float4 c = cv[kk];
                a0 = fmaf(A[kk].x, c.x, a0); a1 = fmaf(A[kk].y, c.y, a1);
                a2 = fmaf(A[kk].z, c.z, a2); a3 = fmaf(A[kk].w, c.w, a3);
            }
            float dotv = (a0 + a1) + (a2 + a3);
            float d2 = fmaf(-2.0f, dotv, x2i + ldsx2[j]);
            if (lexlt(d2, j, dist[KK - 1], idx[KK - 1]))
                insert16x(dist, idx, d2, j);
        }
    } else {
        // overflow fallback (rare): ring incomplete -> exact brute force of
        // the full row (reference by construction). Ring entries skipped.
        #pragma unroll 1
        for (int j = q; j < NP; j += NWV) {
            const float4* cv = (const float4*)(hs + (size_t)j * ND);
            float a0 = 0.f, a1 = 0.f, a2 = 0.f, a3 = 0.f;
            #pragma unroll
            for (int kk = 0; kk < 16; ++kk) {
                float4 c = cv[kk];
                a0 = fmaf(A[kk].x, c.x, a0); a1 = fmaf(A[kk].y, c.y, a1);
                a2 = fmaf(A[kk].z, c.z, a2); a3 = fmaf(A[kk].w, c.w, a3);
            }
            float dotv = (a0 + a1) + (a2 + a3);
            float d2 = fmaf(-2.0f, dotv, x2i + ldsx2[j]);
            if (lexlt(d2, j, dist[KK - 1], idx[KK - 1]))
                insert16x(dist, idx, d2, j);
        }
    }

    // ---- final exact merge (lex): 2 LDS levels (gated) ----
    __syncthreads();
    #pragma unroll 1
    for (int lvl = 0; lvl < 2; ++lvl) {
        const int step = 1 << lvl;
        const int m    = (step << 1) - 1;
        const bool pub = ((q & m) == step);
        const int reg  = q >> (lvl + 1);
        if (pub) {
            #pragma unroll
            for (int k = 0; k < KK; ++k) {
                md[(reg * RB + row) * MS + k] = dist[k];
                mi[(reg * RB + row) * MS + k] = idx[k];
            }
        }
        __syncthreads();
        if ((q & m) == 0) {
            #pragma unroll 1
            for (int k = 0; k < KK; ++k) {
                float v  = md[(reg * RB + row) * MS + k];
                int   jv = mi[(reg * RB + row) * MS + k];
                bool need = lexlt(v, jv, dist[KK - 1], idx[KK - 1]);
                if (!__any(need)) break;
                if (need) insert16x(dist, idx, v, jv);
            }
        }
        __syncthreads();
    }

    // ---- output (wave 0) ----
    if (q == 0) {
        const int off = s * NP;
        const size_t rg = (size_t)off + myrow;
        float* o0 = out + rg * KK;
        float* o1 = out + (size_t)NS * NP * KK + rg * KK;
        float* o2 = out + (size_t)2 * NS * NP * KK + rg * KK;
        #pragma unroll
        for (int k = 0; k < KK; ++k) o0[k] = dist[k];
        #pragma unroll
        for (int k = 0; k < KK; ++k) o1[k] = (float)(idx[k] + off);
        #pragma unroll
        for (int k = 0; k < KK; ++k) o2[k] = (float)(off + myrow);
    }
}

extern "C" void kernel_launch(void* const* d_in, const int* in_sizes, int n_in,
                              void* d_out, int out_size, void* d_ws, size_t ws_size,
                              hipStream_t stream)
{
    const float* h = (const float*)d_in[0];
    float* out = (float*)d_out;
    float*    x2 = (float*)d_ws;                     // 32768 floats (128 KB)
    _Float16* hh = (_Float16*)(x2 + NS * NP);        // 16*2048*64 halves (4 MB)

    hipLaunchKernelGGL(prep_kernel, dim3(NS * NP / 16), dim3(256), 0, stream,
                       h, x2, hh);
    hipLaunchKernelGGL(knn_mfma, dim3(NS * (NP / RB)), dim3(NT), 0, stream,
                       h, hh, x2, out);
}